// Round 2
// baseline (651.474 us; speedup 1.0000x reference)
//
#include <hip/hip_runtime.h>
#include <hip/hip_bf16.h>

#define NQ 20000
#define NKV 20000
#define NE 640000
#define DD 128
#define HH 128

typedef short bf16x8 __attribute__((ext_vector_type(8)));
typedef float f32x4 __attribute__((ext_vector_type(4)));

static __device__ __forceinline__ unsigned short f2b(float f) {
  unsigned u = __builtin_bit_cast(unsigned, f);
  u += 0x7fffu + ((u >> 16) & 1u);  // RNE
  return (unsigned short)(u >> 16);
}
static __device__ __forceinline__ float silu_f(float x) {
  return x / (1.0f + __expf(-x));
}

constexpr int BM  = 64;   // edges (or nodes) per workgroup tile
constexpr int LDA = 264;  // 256 + 8 pad (bf16 elems)
constexpr int LDT = 136;  // 128 + 8 pad

// Convert 8 consecutive floats -> 8 bf16 packed in a uint4
static __device__ __forceinline__ uint4 pack8(const float4* s4) {
  float4 a = s4[0], b = s4[1];
  union { unsigned short u[8]; uint4 q; } p;
  p.u[0] = f2b(a.x); p.u[1] = f2b(a.y); p.u[2] = f2b(a.z); p.u[3] = f2b(a.w);
  p.u[4] = f2b(b.x); p.u[5] = f2b(b.y); p.u[6] = f2b(b.z); p.u[7] = f2b(b.w);
  return p.q;
}

// ---------------- edge kernel: mij = silu(silu([hq|hkv]@We1+be1)@We2+be2),
//                  agg[row] += mij  (fp32 atomics) ----------------
__global__ __launch_bounds__(256, 2) void edge_kernel(
    const float* __restrict__ h_q,
    const float* __restrict__ h_kv,
    const int* __restrict__ erow,
    const int* __restrict__ ecol,
    const float* __restrict__ We1,
    const float* __restrict__ be1,
    const float* __restrict__ We2,
    const float* __restrict__ be2,
    float* __restrict__ mij,
    float* __restrict__ agg,
    int num_tiles) {
  __shared__ __align__(16) unsigned short sA[BM * LDA];
  __shared__ __align__(16) unsigned short sT[BM * LDT];
  __shared__ int sRow[BM];

  const int tid  = threadIdx.x;
  const int wave = tid >> 6;
  const int lane = tid & 63;
  const int quad = lane >> 4;
  const int l16  = lane & 15;
  const int wcol = wave * 32;  // this wave's 32-column strip

  // ---- persistent weight B-fragments: B[k][n], n=l16, k=quad*8+j ----
  bf16x8 wf1[2][8];
  bf16x8 wf2[2][4];
  float bias1[2], bias2[2];
#pragma unroll
  for (int nt = 0; nt < 2; ++nt) {
    const int n = wcol + nt * 16 + l16;
    bias1[nt] = be1[n];
    bias2[nt] = be2[n];
#pragma unroll
    for (int ks = 0; ks < 8; ++ks) {
      const int kb = ks * 32 + quad * 8;
      bf16x8 v;
#pragma unroll
      for (int j = 0; j < 8; ++j) v[j] = (short)f2b(We1[(kb + j) * HH + n]);
      wf1[nt][ks] = v;
    }
#pragma unroll
    for (int ks = 0; ks < 4; ++ks) {
      const int kb = ks * 32 + quad * 8;
      bf16x8 v;
#pragma unroll
      for (int j = 0; j < 8; ++j) v[j] = (short)f2b(We2[(kb + j) * HH + n]);
      wf2[nt][ks] = v;
    }
  }

  for (int tile = blockIdx.x; tile < num_tiles; tile += gridDim.x) {
    const int e0 = tile * BM;

    // ---- stage: 4 threads per edge, each converts 64 floats -> 64 bf16 ----
    {
      const int el = tid >> 2;
      const int part = tid & 3;
      const int e = e0 + el;
      const int r = erow[e];
      const int c = ecol[e];
      if (part == 0) sRow[el] = r;
      const float* src =
          (part < 2 ? h_q + (size_t)r * DD : h_kv + (size_t)c * DD) + (part & 1) * 64;
      uint4* d4 = (uint4*)(sA + el * LDA + part * 64);
      const float4* s4 = (const float4*)src;
#pragma unroll
      for (int i = 0; i < 8; ++i) d4[i] = pack8(s4 + 2 * i);
    }
    __syncthreads();

    // ---- layer 1: [64x256] @ We1 ----
    f32x4 acc[4][2];
#pragma unroll
    for (int mt = 0; mt < 4; ++mt)
#pragma unroll
      for (int nt = 0; nt < 2; ++nt) {
        f32x4 z = {0.0f, 0.0f, 0.0f, 0.0f};
        acc[mt][nt] = z;
      }
#pragma unroll
    for (int ks = 0; ks < 8; ++ks) {
#pragma unroll
      for (int mt = 0; mt < 4; ++mt) {
        bf16x8 a = *(const bf16x8*)(sA + (mt * 16 + l16) * LDA + ks * 32 + quad * 8);
        acc[mt][0] = __builtin_amdgcn_mfma_f32_16x16x32_bf16(a, wf1[0][ks], acc[mt][0], 0, 0, 0);
        acc[mt][1] = __builtin_amdgcn_mfma_f32_16x16x32_bf16(a, wf1[1][ks], acc[mt][1], 0, 0, 0);
      }
    }

    // ---- silu -> sT (C-layout: col=l16, row=quad*4+rg) ----
#pragma unroll
    for (int mt = 0; mt < 4; ++mt)
#pragma unroll
      for (int nt = 0; nt < 2; ++nt)
#pragma unroll
        for (int rg = 0; rg < 4; ++rg) {
          float x = silu_f(acc[mt][nt][rg] + bias1[nt]);
          sT[(mt * 16 + quad * 4 + rg) * LDT + wcol + nt * 16 + l16] = f2b(x);
        }
    __syncthreads();

    // ---- layer 2: [64x128] @ We2 ----
    f32x4 acc2[4][2];
#pragma unroll
    for (int mt = 0; mt < 4; ++mt)
#pragma unroll
      for (int nt = 0; nt < 2; ++nt) {
        f32x4 z = {0.0f, 0.0f, 0.0f, 0.0f};
        acc2[mt][nt] = z;
      }
#pragma unroll
    for (int ks = 0; ks < 4; ++ks) {
#pragma unroll
      for (int mt = 0; mt < 4; ++mt) {
        bf16x8 a = *(const bf16x8*)(sT + (mt * 16 + l16) * LDT + ks * 32 + quad * 8);
        acc2[mt][0] = __builtin_amdgcn_mfma_f32_16x16x32_bf16(a, wf2[0][ks], acc2[mt][0], 0, 0, 0);
        acc2[mt][1] = __builtin_amdgcn_mfma_f32_16x16x32_bf16(a, wf2[1][ks], acc2[mt][1], 0, 0, 0);
      }
    }

    // ---- epilogue: mij store (fp32) + fp32 atomic scatter into agg ----
#pragma unroll
    for (int mt = 0; mt < 4; ++mt) {
#pragma unroll
      for (int rg = 0; rg < 4; ++rg) {
        const int m = mt * 16 + quad * 4 + rg;
        const size_t e = (size_t)(e0 + m);
        const int gr = sRow[m];
#pragma unroll
        for (int nt = 0; nt < 2; ++nt) {
          const int n = wcol + nt * 16 + l16;
          float x = silu_f(acc2[mt][nt][rg] + bias2[nt]);
          mij[e * HH + n] = x;
          atomicAdd(&agg[(size_t)gr * HH + n], x);
        }
      }
    }
    __syncthreads();  // protect sA/sRow/sT against next iteration's staging
  }
}

// ---------------- node kernel: out = h_q + silu([h_q|agg]@Wn1+bn1)@Wn2+bn2 ----
__global__ __launch_bounds__(256, 2) void node_kernel(
    const float* __restrict__ h_q,
    const float* __restrict__ agg,
    const float* __restrict__ Wn1,
    const float* __restrict__ bn1,
    const float* __restrict__ Wn2,
    const float* __restrict__ bn2,
    float* __restrict__ out,
    int num_tiles) {
  __shared__ __align__(16) unsigned short sA[BM * LDA];
  __shared__ __align__(16) unsigned short sT[BM * LDT];

  const int tid  = threadIdx.x;
  const int wave = tid >> 6;
  const int lane = tid & 63;
  const int quad = lane >> 4;
  const int l16  = lane & 15;
  const int wcol = wave * 32;

  bf16x8 wf1[2][8];
  bf16x8 wf2[2][4];
  float bias1[2], bias2[2];
#pragma unroll
  for (int nt = 0; nt < 2; ++nt) {
    const int n = wcol + nt * 16 + l16;
    bias1[nt] = bn1[n];
    bias2[nt] = bn2[n];
#pragma unroll
    for (int ks = 0; ks < 8; ++ks) {
      const int kb = ks * 32 + quad * 8;
      bf16x8 v;
#pragma unroll
      for (int j = 0; j < 8; ++j) v[j] = (short)f2b(Wn1[(kb + j) * HH + n]);
      wf1[nt][ks] = v;
    }
#pragma unroll
    for (int ks = 0; ks < 4; ++ks) {
      const int kb = ks * 32 + quad * 8;
      bf16x8 v;
#pragma unroll
      for (int j = 0; j < 8; ++j) v[j] = (short)f2b(Wn2[(kb + j) * HH + n]);
      wf2[nt][ks] = v;
    }
  }

  for (int tile = blockIdx.x; tile < num_tiles; tile += gridDim.x) {
    const int n0 = tile * BM;

    // ---- stage: parts 0/1 = h_q, parts 2/3 = agg (both fp32 -> bf16) ----
    {
      const int el = tid >> 2;
      const int part = tid & 3;
      const int node = n0 + el;
      uint4* d4 = (uint4*)(sA + el * LDA + part * 64);
      if (node < NQ) {
        const float* src =
            (part < 2 ? h_q + (size_t)node * DD : agg + (size_t)node * HH) + (part & 1) * 64;
        const float4* s4 = (const float4*)src;
#pragma unroll
        for (int i = 0; i < 8; ++i) d4[i] = pack8(s4 + 2 * i);
      } else {
        uint4 z = {0u, 0u, 0u, 0u};
#pragma unroll
        for (int i = 0; i < 8; ++i) d4[i] = z;
      }
    }
    __syncthreads();

    f32x4 acc[4][2];
#pragma unroll
    for (int mt = 0; mt < 4; ++mt)
#pragma unroll
      for (int nt = 0; nt < 2; ++nt) {
        f32x4 z = {0.0f, 0.0f, 0.0f, 0.0f};
        acc[mt][nt] = z;
      }
#pragma unroll
    for (int ks = 0; ks < 8; ++ks) {
#pragma unroll
      for (int mt = 0; mt < 4; ++mt) {
        bf16x8 a = *(const bf16x8*)(sA + (mt * 16 + l16) * LDA + ks * 32 + quad * 8);
        acc[mt][0] = __builtin_amdgcn_mfma_f32_16x16x32_bf16(a, wf1[0][ks], acc[mt][0], 0, 0, 0);
        acc[mt][1] = __builtin_amdgcn_mfma_f32_16x16x32_bf16(a, wf1[1][ks], acc[mt][1], 0, 0, 0);
      }
    }

#pragma unroll
    for (int mt = 0; mt < 4; ++mt)
#pragma unroll
      for (int nt = 0; nt < 2; ++nt)
#pragma unroll
        for (int rg = 0; rg < 4; ++rg) {
          float x = silu_f(acc[mt][nt][rg] + bias1[nt]);
          sT[(mt * 16 + quad * 4 + rg) * LDT + wcol + nt * 16 + l16] = f2b(x);
        }
    __syncthreads();

    f32x4 acc2[4][2];
#pragma unroll
    for (int mt = 0; mt < 4; ++mt)
#pragma unroll
      for (int nt = 0; nt < 2; ++nt) {
        f32x4 z = {0.0f, 0.0f, 0.0f, 0.0f};
        acc2[mt][nt] = z;
      }
#pragma unroll
    for (int ks = 0; ks < 4; ++ks) {
#pragma unroll
      for (int mt = 0; mt < 4; ++mt) {
        bf16x8 a = *(const bf16x8*)(sT + (mt * 16 + l16) * LDT + ks * 32 + quad * 8);
        acc2[mt][0] = __builtin_amdgcn_mfma_f32_16x16x32_bf16(a, wf2[0][ks], acc2[mt][0], 0, 0, 0);
        acc2[mt][1] = __builtin_amdgcn_mfma_f32_16x16x32_bf16(a, wf2[1][ks], acc2[mt][1], 0, 0, 0);
      }
    }

    // ---- epilogue: residual add, bias, fp32 store (no silu on layer 2) ----
#pragma unroll
    for (int mt = 0; mt < 4; ++mt) {
#pragma unroll
      for (int rg = 0; rg < 4; ++rg) {
        const int m = mt * 16 + quad * 4 + rg;
        const int node = n0 + m;
        if (node < NQ) {
#pragma unroll
          for (int nt = 0; nt < 2; ++nt) {
            const int n = wcol + nt * 16 + l16;
            float x = acc2[mt][nt][rg] + bias2[nt] + h_q[(size_t)node * DD + n];
            out[(size_t)node * DD + n] = x;
          }
        }
      }
    }
    __syncthreads();
  }
}

extern "C" void kernel_launch(void* const* d_in, const int* in_sizes, int n_in,
                              void* d_out, int out_size, void* d_ws, size_t ws_size,
                              hipStream_t stream) {
  const float* h_q  = (const float*)d_in[0];
  const float* h_kv = (const float*)d_in[1];
  const int* eidx   = (const int*)d_in[2];
  const float* We1  = (const float*)d_in[3];
  const float* be1  = (const float*)d_in[4];
  const float* We2  = (const float*)d_in[5];
  const float* be2  = (const float*)d_in[6];
  const float* Wn1  = (const float*)d_in[7];
  const float* bn1  = (const float*)d_in[8];
  const float* Wn2  = (const float*)d_in[9];
  const float* bn2  = (const float*)d_in[10];

  float* out = (float*)d_out;   // [NQ*DD] h_q_new, then [NE*HH] mij
  float* agg = (float*)d_ws;    // [NQ*HH] fp32 accumulator

  hipMemsetAsync(d_ws, 0, (size_t)NQ * HH * sizeof(float), stream);

  const int etiles = NE / BM;  // 10000 exactly
  edge_kernel<<<1280, 256, 0, stream>>>(h_q, h_kv, eidx, eidx + NE, We1, be1, We2, be2,
                                        out + (size_t)NQ * DD, agg, etiles);

  const int ntiles = (NQ + BM - 1) / BM;  // 313
  node_kernel<<<ntiles, 256, 0, stream>>>(h_q, agg, Wn1, bn1, Wn2, bn2, out, ntiles);
}